// Round 5
// baseline (152.195 us; speedup 1.0000x reference)
//
#include <hip/hip_runtime.h>
#include <hip/hip_bf16.h>

// BlurredNoise via MFMA implicit GEMM, round 5.
// out[bc][F][t] = scale[F] * sum_j x[bc][t+j] * k[F][j]
// D[m=t][n=F]: A = Toeplitz(x) staged in LDS (4 shifted bf16 copies, built
// in-kernel from fp32 noise via cvt + alignbit + ds_write), B = pre-swizzled
// bf16 filter frags loaded global->VGPR (L2-resident, 2-step-deep prefetch).
// Every wave is IDENTICAL: M=4 t-tiles x N=8 f-tiles (all 128 filters),
// compile-time S table gives exact per-tile k-prefix skipping. 1024 waves,
// barrier-free, no asm waitcnt (compiler-tracked deps only).

#define KS      5000
#define IN_SEQ  9095
#define T_OUT   4096
#define NBC     16
#define NF      128
#define NSTEP   157
#define NG      14                 // ceil(157/12) staging groups of 12 steps
#define CSTRIDE 1056               // bytes; /4 = 264 == 8 mod 32 -> uniform banks
#define XBUF    (4*CSTRIDE)        // 4224 B per buffer (4 shift-copies)
#define S0MAX   157

typedef __attribute__((ext_vector_type(8))) short v8s;
typedef __attribute__((ext_vector_type(4))) float v4f;

// steps needed per 16-filter tile (max f in tile), = ceil((ceil(sr/2)+8)/32),
// safety margin >= 8 taps vs the exact reference formula (extras multiply
// true zeros in the filter).  {7,10,16,25,40,62,99,157}
__device__ __constant__ int d_S_tab[8] = {7, 10, 16, 25, 40, 62, 99, 157};

__device__ __forceinline__ unsigned short f2b(float v) {
  union { __hip_bfloat16 h; unsigned short u; } cv;
  cv.h = __float2bfloat16(v);   // RNE
  return cv.u;
}

// ---- pre-kernel: filters -> B-fragment-ordered bf16, only the live prefix ----
__global__ void build_swz(const float* __restrict__ filt,
                          unsigned short* __restrict__ swz) {
  const int idx = blockIdx.x * 256 + threadIdx.x;
  constexpr int pre[9] = {0, 7, 17, 33, 58, 98, 160, 259, 416};  // prefix of S_tab
  if (idx >= 416 * 512) return;
  const int blk = idx >> 9, w = idx & 511;
  int ft = 0;
  #pragma unroll
  for (int i = 1; i < 8; ++i) if (blk >= pre[i]) ft = i;
  const int s = blk - pre[ft];
  const int q = w >> 7, n = (w >> 3) & 15, j = w & 7;
  const int jg = KS - 32 * (s + 1) + 8 * q + j;
  const float v = (jg >= 0) ? filt[(size_t)(ft * 16 + n) * KS + jg] : 0.0f;
  swz[((size_t)(ft * NSTEP + s) << 9) + w] = f2b(v);
}

// ---- main kernel: 1024 blocks x 64 threads, all waves identical ----
__global__ __launch_bounds__(64, 1) void blur_mfma(
    const float* __restrict__ noise,
    const unsigned short* __restrict__ swz,
    const float* __restrict__ scale,
    float* __restrict__ out)
{
  __shared__ __align__(16) char xb[2 * XBUF];

  const int lane = threadIdx.x;
  const int b  = blockIdx.x;
  const int bc = b >> 6;
  const int t0 = (b & 63) << 6;
  const int m = lane & 15, q = lane >> 4, c = m & 3;
  const float* __restrict__ xn = noise + (size_t)bc * IN_SEQ;

  int S[8];
  #pragma unroll
  for (int n = 0; n < 8; ++n) S[n] = d_S_tab[n];

  // ---- x staging: group G covers steps [12G, 12G+12); LDS copy-c short u
  // holds bf16(x[g0 + u + c]), g0 = t0 + KS - 384(G+1). Lane l supplies
  // shorts [8l, 8l+8) for all 4 copies -> needs x floats [g0+8l, g0+8l+11].
  float4 xr[3];
  auto stage_load = [&](int G) {
    const int g0 = t0 + KS - 384 * (G + 1);
    const int base = g0 + 8 * lane;
    #pragma unroll
    for (int i = 0; i < 3; ++i) {
      const int idx = base + 4 * i;
      float4 v;
      if (idx >= 0 && idx + 4 <= IN_SEQ) {
        v = *(const float4*)(xn + idx);
      } else {  // boundary: element-predicated (OOB taps pair only with B==0)
        v.x = (idx + 0 >= 0 && idx + 0 < IN_SEQ) ? xn[idx + 0] : 0.0f;
        v.y = (idx + 1 >= 0 && idx + 1 < IN_SEQ) ? xn[idx + 1] : 0.0f;
        v.z = (idx + 2 >= 0 && idx + 2 < IN_SEQ) ? xn[idx + 2] : 0.0f;
        v.w = (idx + 3 >= 0 && idx + 3 < IN_SEQ) ? xn[idx + 3] : 0.0f;
      }
      xr[i] = v;
    }
  };
  auto stage_write = [&](int G) {
    const float* f = (const float*)xr;
    unsigned int u6[6];
    #pragma unroll
    for (int j = 0; j < 6; ++j)
      u6[j] = (unsigned)f2b(f[2 * j]) | ((unsigned)f2b(f[2 * j + 1]) << 16);
    auto AL = [](unsigned hi, unsigned lo) { return (lo >> 16) | (hi << 16); };
    char* buf = xb + (G & 1) * XBUF + 16 * lane;
    uint4 w0 = {u6[0], u6[1], u6[2], u6[3]};                                    // shorts 0..7
    uint4 w1 = {AL(u6[1],u6[0]), AL(u6[2],u6[1]), AL(u6[3],u6[2]), AL(u6[4],u6[3])}; // 1..8
    uint4 w2 = {u6[1], u6[2], u6[3], u6[4]};                                    // 2..9
    uint4 w3 = {AL(u6[2],u6[1]), AL(u6[3],u6[2]), AL(u6[4],u6[3]), AL(u6[5],u6[4])}; // 3..10
    *(uint4*)(buf + 0 * CSTRIDE) = w0;
    *(uint4*)(buf + 1 * CSTRIDE) = w1;
    *(uint4*)(buf + 2 * CSTRIDE) = w2;
    *(uint4*)(buf + 3 * CSTRIDE) = w3;
  };

  // A-frag read: byte = c*CSTRIDE + 8*(m>>2) + 16q + 64*(11-ls) + 32*mt {+0,+8}
  const char* xrd = xb + c * CSTRIDE + 8 * (m >> 2) + 16 * q;
  auto read_A = [&](int par, int ls, v8s* dst) {
    const char* p = xrd + par * XBUF + 64 * (11 - ls);
    #pragma unroll
    for (int mt = 0; mt < 4; ++mt) {
      v8s a;
      *(uint2*)&a       = *(const uint2*)(p + 32 * mt);
      *((uint2*)&a + 1) = *(const uint2*)(p + 32 * mt + 8);
      dst[mt] = a;
    }
  };

  const char* bb = (const char*)swz + 16 * lane;
  auto bfrag = [&](int n, int s) {
    return *(const v8s*)(bb + ((size_t)(n * NSTEP + s) << 10));
  };

  v4f acc[4][8];
  const v4f vz = {0.f, 0.f, 0.f, 0.f};
  #pragma unroll
  for (int mt = 0; mt < 4; ++mt)
    #pragma unroll
    for (int n = 0; n < 8; ++n) acc[mt][n] = vz;

  v8s areg[2][4], breg[3][8];

  // prologue
  stage_load(0); stage_write(0);
  stage_load(1);                       // xr now holds group 1 (written at G0.ls5)
  read_A(0, 0, areg[0]);
  #pragma unroll
  for (int n = 0; n < 8; ++n) breg[0][n] = bfrag(n, 0);
  #pragma unroll
  for (int n = 0; n < 8; ++n) if (1 < S[n]) breg[1][n] = bfrag(n, 1);

  #pragma unroll 1
  for (int G = 0; G < NG; ++G) {
    #pragma unroll
    for (int ls = 0; ls < 12; ++ls) {
      const int s = 12 * G + ls;
      if (s >= S0MAX) break;
      // B prefetch, depth 2 (3-slot rotation; slot (ls+2)%3 is free)
      #pragma unroll
      for (int n = 0; n < 8; ++n)
        if (s + 2 < S[n]) breg[(ls + 2) % 3][n] = bfrag(n, s + 2);
      // x staging: write next group's buffer, load the one after
      if (ls == 5) {
        if (G + 1 < NG) stage_write(G + 1);
        if (G + 2 < NG) stage_load(G + 2);
      }
      // A prefetch, 1 step ahead
      if (s + 1 < S0MAX) {
        if (ls == 11) read_A((G + 1) & 1, 0, areg[(ls + 1) & 1]);
        else          read_A(G & 1, ls + 1, areg[(ls + 1) & 1]);
      }
      // MFMA: 4 m-tiles x live n-tiles
      #pragma unroll
      for (int n = 0; n < 8; ++n) {
        if (s < S[n]) {
          #pragma unroll
          for (int mt = 0; mt < 4; ++mt)
            acc[mt][n] = __builtin_amdgcn_mfma_f32_16x16x32_bf16(
                areg[ls & 1][mt], breg[ls % 3][n], acc[mt][n], 0, 0, 0);
        }
      }
    }
  }

  // epilogue: D col=lane&15 -> filter-in-tile, row=4q+reg -> t offset
  #pragma unroll
  for (int n = 0; n < 8; ++n) {
    const int F = 16 * n + m;
    const float sc = scale[F];
    #pragma unroll
    for (int mt = 0; mt < 4; ++mt) {
      v4f o = acc[mt][n] * sc;
      *(v4f*)(out + (size_t)(bc * NF + F) * T_OUT + t0 + 16 * mt + 4 * q) = o;
    }
  }
}

extern "C" void kernel_launch(void* const* d_in, const int* in_sizes, int n_in,
                              void* d_out, int out_size, void* d_ws, size_t ws_size,
                              hipStream_t stream) {
  const float* noise = (const float*)d_in[0];   // (2, 8, 9095) fp32
  const float* filt  = (const float*)d_in[1];   // (128, 5000) fp32
  const float* scale = (const float*)d_in[2];   // (1, 128, 1) fp32
  float* out = (float*)d_out;                   // (2, 1024, 4096) fp32

  unsigned short* swz = (unsigned short*)d_ws;  // 8*157*512 shorts (sparse-built)

  build_swz<<<832, 256, 0, stream>>>(filt, swz);
  blur_mfma<<<1024, 64, 0, stream>>>(noise, swz, scale, out);
}

// Round 8
// 123.971 us; speedup vs baseline: 1.2277x; 1.2277x over previous
//
#include <hip/hip_runtime.h>
#include <hip/hip_bf16.h>

// BlurredNoise via MFMA implicit GEMM, round 8 = round 7 minus a restrict-UB.
// out[bc][F][t] = scale[F] * sum_j x[bc][t+j] * k[F][j]
// k-loop in compile-time segments of constant width W (8..1): ALL global loads
// (B-frags + x staging) are unconditional straight-line -> exact vmcnt
// brackets -> L2 latency hidden by register-rotation prefetch depth D.
// R6/R7 NaN root cause: run_seg took xb AND xrd as __restrict__ params that
// alias the same LDS -> compiler could hoist ds_reads above ds_writes ->
// uninitialized-LDS bf16 NaN patterns fed MFMA. Fix: single non-restrict xb
// pointer, read pointer derived from it inside (may-alias, order preserved).

#define KS      5000
#define IN_SEQ  9095
#define T_OUT   4096
#define NBC     16
#define NF      128
#define NSTEP   157
#define SWZSTEP 176               // padded per-tile step stride
#define CSTRIDE 1056              // bytes; /4 = 264 == 8 mod 32 -> uniform banks
#define XBUF    (4*CSTRIDE)       // 4224 B per parity buffer
#define XPS     9344              // padded x row stride (floats), front pad 32
#define SWZ_BYTES (8*SWZSTEP*512*2)   // 1,441,792

typedef __attribute__((ext_vector_type(8))) short v8s;
typedef __attribute__((ext_vector_type(4))) float v4f;

__device__ __forceinline__ unsigned short f2b(float v) {
  union { __hip_bfloat16 h; unsigned short u; } cv;
  cv.h = __float2bfloat16(v);   // RNE
  return cv.u;
}

// ---- fused pre-kernel: (a) filters -> B-frag bf16; (b) zero-padded x copy ----
__global__ void build_pre(const float* __restrict__ filt,
                          const float* __restrict__ noise,
                          unsigned short* __restrict__ swz,
                          float* __restrict__ xpad) {
  const int b = blockIdx.x;
  if (b < 314) {                       // swz job: thread -> 8 consecutive shorts
    const int i = b * 256 + threadIdx.x;
    if (i >= 8 * NSTEP * 64) return;
    const int n  = i & 15;
    const int q  = (i >> 4) & 3;
    const int sb = i >> 6;
    const int ft = sb / NSTEP;
    const int s  = sb - ft * NSTEP;
    const int jg0 = KS - 32 * (s + 1) + 8 * q;
    const float* row = filt + (size_t)(ft * 16 + n) * KS;
    unsigned short o[8];
    #pragma unroll
    for (int j = 0; j < 8; ++j) {
      int jg = jg0 + j;
      int jc = jg < 0 ? 0 : jg;          // clamp ADDRESS, select VALUE
      float v = (jg >= 0) ? row[jc] : 0.0f;
      o[j] = f2b(v);
    }
    *(uint4*)(swz + (((size_t)(ft * SWZSTEP + s)) << 9) + (q << 7) + (n << 3)) = *(uint4*)o;
  } else {                             // xpad job: 16 x XPS, zeros outside
    const int i = (b - 314) * 256 + threadIdx.x;
    if (i >= NBC * XPS) return;
    const int r = i / XPS;
    const int pcol = i - r * XPS;
    const int lg = pcol - 32;
    xpad[i] = (lg >= 0 && lg < IN_SEQ) ? noise[r * IN_SEQ + lg] : 0.0f;
  }
}

// ---- one constant-width segment of the k-loop ----
// W: live tiles (n in [8-W,8)); U: steps/group; NG: groups; SB: first step;
// D: B-prefetch depth (U % D == 0). xb: LDS base (NO restrict — stage_write
// stores and A-reads load through the same provenance, order preserved).
template<int W, int U, int NG, int SB, int D>
__device__ __forceinline__ void run_seg(
    const char* __restrict__ bb, const float* __restrict__ xn,
    char* xb, int xrd_off, int t0, int lane, v4f (&acc)[4][8])
{
  v8s breg[D][W];
  v8s areg[2][4];
  float4 xr[3];
  const char* xrd = xb + xrd_off;      // may-alias xb: ds ordering preserved

  const char* sp[W];
  #pragma unroll
  for (int w = 0; w < W; ++w)
    sp[w] = bb + (((size_t)((8 - W + w) * SWZSTEP + SB)) << 10);

  auto stage_load = [&](int gg) {      // unconditional, aligned (padded buffer)
    const int g0 = t0 + KS - 32 * (SB + (gg + 1) * U);
    #pragma unroll
    for (int ii = 0; ii < 3; ++ii)
      xr[ii] = *(const float4*)(xn + (g0 + 8 * lane + 4 * ii));
  };
  auto stage_write = [&](int parity) { // xr -> 4 shifted bf16 LDS copies
    const float* f = (const float*)xr;
    unsigned u6[6];
    #pragma unroll
    for (int j = 0; j < 6; ++j)
      u6[j] = (unsigned)f2b(f[2 * j]) | ((unsigned)f2b(f[2 * j + 1]) << 16);
    auto AL = [](unsigned hi, unsigned lo) { return (lo >> 16) | (hi << 16); };
    char* buf = xb + parity * XBUF + 16 * lane;
    uint4 w0 = {u6[0], u6[1], u6[2], u6[3]};
    uint4 w1 = {AL(u6[1],u6[0]), AL(u6[2],u6[1]), AL(u6[3],u6[2]), AL(u6[4],u6[3])};
    uint4 w2 = {u6[1], u6[2], u6[3], u6[4]};
    uint4 w3 = {AL(u6[2],u6[1]), AL(u6[3],u6[2]), AL(u6[4],u6[3]), AL(u6[5],u6[4])};
    *(uint4*)(buf + 0 * CSTRIDE) = w0;
    *(uint4*)(buf + 1 * CSTRIDE) = w1;
    *(uint4*)(buf + 2 * CSTRIDE) = w2;
    *(uint4*)(buf + 3 * CSTRIDE) = w3;
  };
  auto read_A = [&](const char* p, v8s (&dst)[4]) {
    #pragma unroll
    for (int mt = 0; mt < 4; ++mt) {
      v8s a;
      *(uint2*)&a       = *(const uint2*)(p + 32 * mt);
      *((uint2*)&a + 1) = *(const uint2*)(p + 32 * mt + 8);
      dst[mt] = a;
    }
  };

  // prologue: B depth-D, x group0 staged + group1 loaded, A step SB
  #pragma unroll
  for (int d = 0; d < D; ++d)
    #pragma unroll
    for (int w = 0; w < W; ++w)
      breg[d][w] = *(const v8s*)(sp[w] + (d << 10));
  stage_load(0);
  stage_write(0);
  stage_load(NG > 1 ? 1 : 0);
  read_A(xrd + 64 * (U - 1), areg[0]);

  #pragma unroll 1
  for (int g = 0; g < NG; ++g) {
    #pragma unroll
    for (int i = 0; i < U; ++i) {
      if (i == 1) stage_write((g + 1) & 1);   // garbage parity-write if g+1==NG (unread)
      if (i == 2) { int gg = g + 2; gg = gg > NG - 1 ? NG - 1 : gg; stage_load(gg); }
      // A prefetch for next step
      {
        const char* pn;
        if (i + 1 < U) {
          pn = xrd + (g & 1) * XBUF + 64 * (U - 2 - i);
        } else {
          int gn = (g + 1 < NG) ? (g + 1) : g;
          pn = xrd + (gn & 1) * XBUF + 64 * (U - 1);
        }
        read_A(pn, areg[(i + 1) & 1]);
      }
      // MFMA: use B slot i%D (loaded D steps ago), then refill same slot
      #pragma unroll
      for (int w = 0; w < W; ++w)
        #pragma unroll
        for (int mt = 0; mt < 4; ++mt)
          acc[mt][8 - W + w] = __builtin_amdgcn_mfma_f32_16x16x32_bf16(
              areg[i & 1][mt], breg[i % D][w], acc[mt][8 - W + w], 0, 0, 0);
      #pragma unroll
      for (int w = 0; w < W; ++w)
        breg[i % D][w] = *(const v8s*)(sp[w] + ((i + D) << 10));
    }
    #pragma unroll
    for (int w = 0; w < W; ++w) sp[w] += (U << 10);
  }
}

// ---- main kernel: 1024 blocks x 64 threads, identical waves, barrier-free ----
__global__ __launch_bounds__(64, 1) void blur_mfma(
    const float* __restrict__ xpad,
    const unsigned short* __restrict__ swz,
    const float* __restrict__ scale,
    float* __restrict__ out)
{
  __shared__ __align__(16) char xb[2 * XBUF];
  const int lane = threadIdx.x;
  const int b  = blockIdx.x;
  const int bc = b >> 6;
  const int t0 = (b & 63) << 6;
  const int m = lane & 15, q = lane >> 4, c = m & 3;
  const float* __restrict__ xn = xpad + (size_t)bc * XPS + 32;  // logical origin
  const char* bb = (const char*)swz + 16 * lane;
  const int xrd_off = c * CSTRIDE + 8 * (m >> 2) + 16 * q;

  v4f acc[4][8];
  const v4f vz = {0.f, 0.f, 0.f, 0.f};
  #pragma unroll
  for (int mt = 0; mt < 4; ++mt)
    #pragma unroll
    for (int n = 0; n < 8; ++n) acc[mt][n] = vz;

  // segments: <W, U, NG, SB, D>; S' = {8,12,16,28,40,64,100,157}
  run_seg<8,  8, 1,   0,  2>(bb, xn, xb, xrd_off, t0, lane, acc);
  run_seg<7,  4, 1,   8,  2>(bb, xn, xb, xrd_off, t0, lane, acc);
  run_seg<6,  4, 1,  12,  2>(bb, xn, xb, xrd_off, t0, lane, acc);
  run_seg<5, 12, 1,  16,  3>(bb, xn, xb, xrd_off, t0, lane, acc);
  run_seg<4, 12, 1,  28,  4>(bb, xn, xb, xrd_off, t0, lane, acc);
  run_seg<3, 12, 2,  40,  6>(bb, xn, xb, xrd_off, t0, lane, acc);
  run_seg<2, 12, 3,  64,  6>(bb, xn, xb, xrd_off, t0, lane, acc);
  run_seg<1, 12, 4, 100, 12>(bb, xn, xb, xrd_off, t0, lane, acc);
  run_seg<1,  9, 1, 148,  9>(bb, xn, xb, xrd_off, t0, lane, acc);

  // epilogue: D col=lane&15 -> filter-in-tile, row=4q+reg -> t offset
  #pragma unroll
  for (int n = 0; n < 8; ++n) {
    const int F = 16 * n + m;
    const float sc = scale[F];
    #pragma unroll
    for (int mt = 0; mt < 4; ++mt) {
      v4f o = acc[mt][n] * sc;
      *(v4f*)(out + (size_t)(bc * NF + F) * T_OUT + t0 + 16 * mt + 4 * q) = o;
    }
  }
}

extern "C" void kernel_launch(void* const* d_in, const int* in_sizes, int n_in,
                              void* d_out, int out_size, void* d_ws, size_t ws_size,
                              hipStream_t stream) {
  const float* noise = (const float*)d_in[0];   // (2, 8, 9095) fp32
  const float* filt  = (const float*)d_in[1];   // (128, 5000) fp32
  const float* scale = (const float*)d_in[2];   // (1, 128, 1) fp32
  float* out = (float*)d_out;                   // (2, 1024, 4096) fp32

  unsigned short* swz = (unsigned short*)d_ws;              // 1.44 MB
  float* xpad = (float*)((char*)d_ws + SWZ_BYTES);          // 16 x 9344 fp32

  const int pad_blocks = (NBC * XPS + 255) / 256;           // 584
  build_pre<<<314 + pad_blocks, 256, 0, stream>>>(filt, noise, swz, xpad);
  blur_mfma<<<1024, 64, 0, stream>>>(xpad, swz, scale, out);
}